// Round 1
// baseline (322.549 us; speedup 1.0000x reference)
//
#include <hip/hip_runtime.h>
#include <math.h>

#define BB 8
#define NCLS 16
#define NPIX 16384
#define CHN 256
#define MAXV 200
#define SORTN 2048

typedef unsigned long long ull;

// ---------------- ws layout (bytes) ----------------
// 0     : double acc
// 16    : int ctr[3]        (last-block counters: histplan, accum, inter)
// 64    : int counts[128]
// 1024  : int plan[536]: [0]=n_view [1]=k [2]=P [3]=D,
//         chan[16]@+4, pimg[128]@+20, pcls[128]@+148, pmap[128]@+276, Lp[128]@+404
// 4096  : ull thrKey[128]
// 8192  : float pos_sum[2048]   (zeroed)
// 16384 : float posnorm[128]
// 32768 : float cert[131072]    (512 KB)
// (everything above 16384 is fully overwritten each launch; 0..16384 memset)

// hist over predict + (in the last block to finish) the plan build.
// counts are written with device-scope atomics and read back with atomic RMWs,
// so per-XCD L2 non-coherence cannot serve stale lines.
__global__ __launch_bounds__(256) void k_histplan(const int* __restrict__ predict,
                                                  int* __restrict__ counts,
                                                  int* __restrict__ plan,
                                                  int* __restrict__ ctr) {
    __shared__ int h[NCLS];
    __shared__ int lastFlag;
    int tid = threadIdx.x;
    if (tid < NCLS) h[tid] = 0;
    __syncthreads();
    int base = blockIdx.x * 256;
    int b = base >> 14;
    int v = predict[base + tid];
    if (v >= 0 && v < NCLS) atomicAdd(&h[v], 1);
    __syncthreads();
    if (tid < NCLS && h[tid] > 0) atomicAdd(&counts[b * NCLS + tid], h[tid]);
    __threadfence();            // every wave drains its global atomic before the barrier
    __syncthreads();
    if (tid == 0) lastFlag = (atomicAdd(ctr, 1) == 511);
    __syncthreads();
    if (!lastFlag) return;

    // ---------------- plan (runs exactly once) ----------------
    __shared__ int c[128];
    __shared__ int sc[128];
    __shared__ int mn[128];
    __shared__ int present[NCLS];
    int* chan = plan + 4;
    int* pimg = plan + 20;
    int* pcls = plan + 148;
    int* pmap = plan + 276;
    int* Lp   = plan + 404;
    if (tid < 128) c[tid] = atomicAdd(&counts[tid], 0);  // coherent read
    if (tid < NCLS) present[tid] = 0;
    __syncthreads();
    int e = 0;
    if (tid < 128) {
        if (c[tid] > 0) atomicOr(&present[tid & 15], 1);
        e = (c[tid] >= MAXV) ? 1 : 0;
        sc[tid] = e;
        mn[tid] = e ? c[tid] : 0x7fffffff;
    }
    __syncthreads();
    for (int off = 1; off < 128; off <<= 1) {
        int add = 0;
        if (tid < 128 && tid >= off) add = sc[tid - off];
        __syncthreads();
        if (tid < 128) sc[tid] += add;
        __syncthreads();
    }
    for (int s = 64; s > 0; s >>= 1) {
        if (tid < s) mn[tid] = min(mn[tid], mn[tid + s]);
        __syncthreads();
    }
    if (tid < 128) {
        pmap[tid] = e ? (sc[tid] - 1) : -1;
        if (e) {
            int p = sc[tid] - 1;
            pimg[p] = tid >> 4; pcls[p] = tid & 15; Lp[p] = c[tid];
        }
    }
    if (tid == 0) {
        int D = 0;
        for (int vv = 0; vv < NCLS; ++vv) if (present[vv]) chan[D++] = vv;
        int nview = mn[0];
        plan[0] = nview; plan[1] = nview / 2; plan[2] = sc[127]; plan[3] = D;
    }
}

// single-phase top-2 certainty: one block owns 256 pixels x all 256 channels.
// 4 channel-slices of 64 channels each, merged through LDS. float4 x 8-deep
// batched loads (16B/lane, wave-contiguous 1KB transactions).
__global__ __launch_bounds__(256) void k_cert(const float* __restrict__ feats,
                                              float* __restrict__ cert) {
    __shared__ float2 sh[4 * 256];
    int tid = threadIdx.x;
    int lane = tid & 63;          // pixel-quad index within the tile
    int slice = tid >> 6;         // channel slice 0..3
    int b = blockIdx.x >> 6;      // 64 tiles per image
    int tile = blockIdx.x & 63;
    int n4 = tile * 256 + lane * 4;
    const float* fb = feats + (size_t)b * CHN * NPIX + (size_t)(slice * 64) * NPIX + n4;
    float m1[4] = {-INFINITY, -INFINITY, -INFINITY, -INFINITY};
    float m2[4] = {-INFINITY, -INFINITY, -INFINITY, -INFINITY};
    for (int cb = 0; cb < 64; cb += 8) {
        float4 xs[8];
#pragma unroll
        for (int u = 0; u < 8; ++u)
            xs[u] = *(const float4*)(fb + (size_t)(cb + u) * NPIX);
#pragma unroll
        for (int u = 0; u < 8; ++u) {
            float xv[4] = {xs[u].x, xs[u].y, xs[u].z, xs[u].w};
#pragma unroll
            for (int q = 0; q < 4; ++q) {
                float val = xv[q];
                if (val > m1[q]) { m2[q] = m1[q]; m1[q] = val; }
                else if (val > m2[q]) m2[q] = val;
            }
        }
    }
#pragma unroll
    for (int q = 0; q < 4; ++q)
        sh[slice * 256 + lane * 4 + q] = make_float2(m1[q], m2[q]);
    __syncthreads();
    float M1 = -INFINITY, M2 = -INFINITY;
#pragma unroll
    for (int j = 0; j < 4; ++j) {
        float2 pm = sh[j * 256 + tid];
        if (pm.x > M1) { M2 = fmaxf(M1, pm.y); M1 = pm.x; }
        else           { M2 = fmaxf(M2, pm.x); }
    }
    cert[b * NPIX + tile * 256 + tid] = M1 - M2;
}

// per-(b,v) radix-select the kv-th largest 64-bit key -> threshold
__global__ __launch_bounds__(512) void k_sel(const int* __restrict__ predict,
                                             const float* __restrict__ cert,
                                             const int* __restrict__ plan,
                                             ull* __restrict__ thrKey) {
    __shared__ ull keys[SORTN];
    __shared__ int whist[8][256];
    __shared__ int scan[257];
    __shared__ int wtot[4];
    __shared__ int lcnt;
    __shared__ ull sprefix;
    __shared__ int sremain;
    __shared__ int sdone;
    int tid = threadIdx.x;
    int lane = tid & 63, wv = tid >> 6;
    int b = blockIdx.x >> 4, v = blockIdx.x & 15;
    const int* pmap = plan + 276;
    int p = pmap[b * NCLS + v];
    if (p < 0) return;
    if (tid == 0) { lcnt = 0; sprefix = 0; sdone = 0; }
    __syncthreads();
    for (int n = tid; n < NPIX; n += 512) {
        bool match = (predict[b * NPIX + n] == v);
        ull mask = __ballot(match);
        if (mask) {
            int leader = __ffsll((long long)mask) - 1;
            int basepos = 0;
            if (lane == leader) basepos = atomicAdd(&lcnt, __popcll(mask));
            basepos = __shfl(basepos, leader, 64);
            if (match) {
                int pos = basepos + __popcll(mask & ((1ull << lane) - 1));
                if (pos < SORTN) {
                    unsigned int m = __float_as_uint(cert[b * NPIX + n]) | 0x80000000u;
                    keys[pos] = ((ull)m << 32) | (ull)(0xFFFFFFFFu - (unsigned)n);
                }
            }
        }
    }
    __syncthreads();
    int L = lcnt < SORTN ? lcnt : SORTN;
    int kv = plan[1] < L ? plan[1] : L;
    if (tid == 0) sremain = kv;
    __syncthreads();
    for (int shift = 56; shift >= 0; shift -= 8) {
        if (sdone) break;
        for (int i = tid; i < 8 * 256; i += 512) ((int*)whist)[i] = 0;
        ull pref = sprefix;
        int rem = sremain;
        __syncthreads();
        ull maskHi = (shift == 56) ? 0ULL : (~0ULL) << (shift + 8);
        for (int i = tid; i < L; i += 512) {
            ull kk = keys[i];
            if ((kk & maskHi) == pref)
                atomicAdd(&whist[wv][(int)((kk >> shift) & 255)], 1);
        }
        __syncthreads();
        int s = 0;
        if (tid < 256) {
            for (int w = 0; w < 8; ++w) s += whist[w][tid];
            for (int off = 1; off < 64; off <<= 1) {
                int o = __shfl_down(s, off, 64);
                if (lane + off < 64) s += o;
            }
            if (lane == 0) wtot[wv] = s;
        }
        __syncthreads();
        if (tid < 256) {
            int offs = 0;
            for (int w2 = wv + 1; w2 < 4; ++w2) offs += wtot[w2];
            s += offs;
            scan[tid] = s;
            if (tid == 0) scan[256] = 0;
        }
        __syncthreads();
        if (tid < 256) {
            int nxt = scan[tid + 1];
            if (s >= rem && nxt < rem) {
                sprefix = pref | ((ull)tid << shift);
                sremain = rem - nxt;
                if (s == rem) sdone = 1;
            }
        }
        __syncthreads();
    }
    if (tid == 0) thrKey[p] = sprefix;
}

// coalesced sweep accumulation of the certainty-top-k class means;
// the last block to finish also computes the intra (class-vs-class) loss term.
__global__ __launch_bounds__(512) void k_accum(const float* __restrict__ feats,
                                               const int* __restrict__ predict,
                                               const float* __restrict__ cert,
                                               const int* __restrict__ plan,
                                               const ull* __restrict__ thrKey,
                                               float* __restrict__ pos_sum,
                                               float* __restrict__ posnorm,
                                               double* __restrict__ acc,
                                               int* __restrict__ ctr) {
    __shared__ float gacc[NCLS * 16];
    __shared__ int lastFlag;
    int tid = threadIdx.x;
    int t = blockIdx.x * 512 + tid;
    int b = (blockIdx.x * 512) >> 14;
    int n = t & (NPIX - 1);
    const int* chan = plan + 4;
    const int* pmap = plan + 276;
    int D = plan[3];
    if (tid < NCLS * 16) gacc[tid] = 0.f;
    __syncthreads();
    int v = predict[t];
    if (v >= 0 && v < NCLS) {
        int p = pmap[b * NCLS + v];
        if (p >= 0) {
            unsigned int m = __float_as_uint(cert[t]) | 0x80000000u;
            ull key = ((ull)m << 32) | (ull)(0xFFFFFFFFu - (unsigned)n);
            if (key >= thrKey[p]) {
                const float* fb = feats + ((size_t)(b * CHN) << 14) + n;
                if (D == 16) {
                    float x[16];
#pragma unroll
                    for (int d = 0; d < 16; ++d)
                        x[d] = fb[(size_t)chan[d] << 14];
#pragma unroll
                    for (int d = 0; d < 16; ++d)
                        atomicAdd(&gacc[v * 16 + d], x[d]);
                } else {
                    for (int d = 0; d < D; ++d)
                        atomicAdd(&gacc[v * 16 + d], fb[(size_t)chan[d] << 14]);
                }
            }
        }
    }
    __syncthreads();
    if (tid < NCLS * 16) {
        int p = pmap[b * NCLS + (tid >> 4)];
        if (p >= 0 && gacc[tid] != 0.f) atomicAdd(&pos_sum[p * 16 + (tid & 15)], gacc[tid]);
    }
    __threadfence();
    __syncthreads();
    if (tid == 0) lastFlag = (atomicAdd(ctr, 1) == 255);
    __syncthreads();
    if (!lastFlag) return;

    // ---------------- intra loss (runs exactly once) ----------------
    __shared__ float ppd[128 * 16];
    __shared__ float nr[128];
    __shared__ int cl[128];
    __shared__ double red[512];
    int P = plan[2];
    const int* pcls = plan + 148;
    for (int i = tid; i < P * 16; i += 512) ppd[i] = atomicAdd(&pos_sum[i], 0.f);
    __syncthreads();
    for (int p = tid; p < P; p += 512) {
        float s = 0;
        for (int d = 0; d < D; ++d) { float x = ppd[p * 16 + d]; s += x * x; }
        float nn = sqrtf(s);
        nr[p] = nn; posnorm[p] = nn; cl[p] = pcls[p];
    }
    __syncthreads();
    double num = 0; int cnt = 0;
    for (int idx = tid; idx < P * P; idx += 512) {
        int i = idx / P, j = idx - i * P;
        if (cl[i] != cl[j]) {
            float dot = 0;
            for (int d = 0; d < D; ++d) dot += ppd[i * 16 + d] * ppd[j * 16 + d];
            num += (double)(dot / (nr[i] * nr[j])) + 1.0;
            cnt++;
        }
    }
    red[tid] = num; __syncthreads();
    for (int s = 256; s > 0; s >>= 1) { if (tid < s) red[tid] += red[tid + s]; __syncthreads(); }
    double totnum = red[0]; __syncthreads();
    red[tid] = (double)cnt; __syncthreads();
    for (int s = 256; s > 0; s >>= 1) { if (tid < s) red[tid] += red[tid + s]; __syncthreads(); }
    if (tid == 0) atomicAdd(acc, totnum / red[0]);
}

// inter loss over all class pixels; the last block writes the final output.
__global__ __launch_bounds__(256) void k_inter(const float* __restrict__ feats,
                                               const int* __restrict__ predict,
                                               const int* __restrict__ plan,
                                               const float* __restrict__ pos_,
                                               const float* __restrict__ posnorm,
                                               double* __restrict__ acc,
                                               int* __restrict__ ctr,
                                               float* __restrict__ out) {
    __shared__ double red[256];
    int tid = threadIdx.x;
    int t = blockIdx.x * 256 + tid;
    int b = t >> 14, n = t & (NPIX - 1);
    int P = plan[2], D = plan[3];
    const int* chan = plan + 4;
    const int* pmap = plan + 276;
    const int* Lp = plan + 404;
    double term = 0;
    int v = predict[t];
    if (v >= 0 && v < NCLS) {
        int p = pmap[b * NCLS + v];
        if (p >= 0) {
            const float* fb = feats + ((size_t)(b * CHN) << 14) + n;
            float dot = 0, nv = 0;
            if (D == 16) {
                float x[16];
#pragma unroll
                for (int d = 0; d < 16; ++d) x[d] = fb[(size_t)chan[d] << 14];
#pragma unroll
                for (int d = 0; d < 16; ++d) {
                    float y = pos_[p * 16 + d];
                    dot += x[d] * y; nv += x[d] * x[d];
                }
            } else {
                for (int d = 0; d < D; ++d) {
                    float x = fb[(size_t)chan[d] << 14];
                    float y = pos_[p * 16 + d];
                    dot += x * y; nv += x * x;
                }
            }
            float den = fmaxf(sqrtf(nv) * posnorm[p], 1e-8f);
            term = (1.0 - (double)(dot / den)) / ((double)Lp[p] * (double)P);
        }
    }
    red[tid] = term; __syncthreads();
    for (int s = 128; s > 0; s >>= 1) { if (tid < s) red[tid] += red[tid + s]; __syncthreads(); }
    if (tid == 0) {
        atomicAdd(acc, red[0]);
        __threadfence();
        if (atomicAdd(ctr, 1) == 511) out[0] = (float)atomicAdd(acc, 0.0);
    }
}

extern "C" void kernel_launch(void* const* d_in, const int* in_sizes, int n_in,
                              void* d_out, int out_size, void* d_ws, size_t ws_size,
                              hipStream_t stream) {
    const float* feats  = (const float*)d_in[0];
    const int* predict  = (const int*)d_in[2];
    char* ws = (char*)d_ws;
    double* acc     = (double*)ws;
    int* ctr        = (int*)(ws + 16);
    int* counts     = (int*)(ws + 64);
    int* plan       = (int*)(ws + 1024);
    ull* thrKey     = (ull*)(ws + 4096);
    float* pos_sum  = (float*)(ws + 8192);
    float* posnorm  = (float*)(ws + 16384);
    float* cert     = (float*)(ws + 32768);
    float* out      = (float*)d_out;

    hipMemsetAsync(ws, 0, 16384, stream);
    k_histplan<<<512, 256, 0, stream>>>(predict, counts, plan, ctr + 0);
    k_cert    <<<512, 256, 0, stream>>>(feats, cert);
    k_sel     <<<128, 512, 0, stream>>>(predict, cert, plan, thrKey);
    k_accum   <<<256, 512, 0, stream>>>(feats, predict, cert, plan, thrKey, pos_sum, posnorm, acc, ctr + 1);
    k_inter   <<<512, 256, 0, stream>>>(feats, predict, plan, pos_sum, posnorm, acc, ctr + 2, out);
}

// Round 2
// 267.704 us; speedup vs baseline: 1.2049x; 1.2049x over previous
//
#include <hip/hip_runtime.h>
#include <math.h>

#define BB 8
#define NCLS 16
#define NPIX 16384
#define CHN 256
#define MAXV 200
#define SORTN 2048

typedef unsigned long long ull;

// ---------------- ws layout (bytes) ----------------
// 0       : double acc
// 64      : int counts[128]
// 1024    : int plan[536]: [0]=n_view [1]=k [2]=P [3]=D,
//           chan[16]@+4, pimg[128]@+20, pcls[128]@+148, pmap[128]@+276, Lp[128]@+404
// 4096    : ull thrKey[128]
// 8192    : float pos_sum[2048]   (zeroed)
// 16384   : float posnorm[128]
// 32768   : float cert[131072]    (512 KB)
// 1048576 : float2 part[NC*8*16384]
//
// NOTE (round-1 lesson): no __threadfence / last-block-done fusion anywhere.
// Device-scope fences on the 8-XCD MI355X force L2 writeback traffic and cost
// ~50 us in aggregate. All cross-kernel ordering uses in-stream dispatch
// boundaries (runtime-managed cache flush), which round-0 verified correct.

__global__ __launch_bounds__(256) void k_hist(const int* __restrict__ predict,
                                              int* __restrict__ counts) {
    __shared__ int h[NCLS];
    int tid = threadIdx.x;
    if (tid < NCLS) h[tid] = 0;
    __syncthreads();
    int base = blockIdx.x * 256;
    int b = base >> 14;
    int v = predict[base + tid];
    if (v >= 0 && v < NCLS) atomicAdd(&h[v], 1);
    __syncthreads();
    if (tid < NCLS && h[tid] > 0) atomicAdd(&counts[b * NCLS + tid], h[tid]);
}

__global__ __launch_bounds__(256) void k_plan(const int* __restrict__ counts,
                                              int* __restrict__ plan) {
    __shared__ int c[128];
    __shared__ int sc[128];
    __shared__ int mn[128];
    __shared__ int present[NCLS];
    int tid = threadIdx.x;
    int* chan = plan + 4;
    int* pimg = plan + 20;
    int* pcls = plan + 148;
    int* pmap = plan + 276;
    int* Lp   = plan + 404;
    if (tid < 128) c[tid] = counts[tid];
    if (tid < NCLS) present[tid] = 0;
    __syncthreads();
    int e = 0;
    if (tid < 128) {
        if (c[tid] > 0) atomicOr(&present[tid & 15], 1);
        e = (c[tid] >= MAXV) ? 1 : 0;
        sc[tid] = e;
        mn[tid] = e ? c[tid] : 0x7fffffff;
    }
    __syncthreads();
    for (int off = 1; off < 128; off <<= 1) {
        int add = 0;
        if (tid < 128 && tid >= off) add = sc[tid - off];
        __syncthreads();
        if (tid < 128) sc[tid] += add;
        __syncthreads();
    }
    for (int s = 64; s > 0; s >>= 1) {
        if (tid < s) mn[tid] = min(mn[tid], mn[tid + s]);
        __syncthreads();
    }
    if (tid < 128) {
        pmap[tid] = e ? (sc[tid] - 1) : -1;
        if (e) {
            int p = sc[tid] - 1;
            pimg[p] = tid >> 4; pcls[p] = tid & 15; Lp[p] = c[tid];
        }
    }
    if (tid == 0) {
        int D = 0;
        for (int v = 0; v < NCLS; ++v) if (present[v]) chan[D++] = v;
        int nview = mn[0];
        plan[0] = nview; plan[1] = nview / 2; plan[2] = sc[127]; plan[3] = D;
    }
}

// phase 1: explicit 8-deep load batching (loads issued before ANY compare use).
// Blocks 0..511 additionally histogram a 256-entry slice of predict (fence-free
// k_hist fusion: independent work, consumed only by the NEXT dispatch).
template <int NC>
__global__ __launch_bounds__(256) void k_cert1h(const float* __restrict__ feats,
                                                const int* __restrict__ predict,
                                                float2* __restrict__ part,
                                                int* __restrict__ counts) {
    int bid = blockIdx.x;                  // BB * 16 * NC blocks (>= 512)
    int tid = threadIdx.x;
    if (bid < 512) {
        __shared__ int h[NCLS];
        if (tid < NCLS) h[tid] = 0;
        __syncthreads();
        int v = predict[bid * 256 + tid];
        if (v >= 0 && v < NCLS) atomicAdd(&h[v], 1);
        __syncthreads();
        if (tid < NCLS && h[tid] > 0) atomicAdd(&counts[(bid >> 6) * NCLS + tid], h[tid]);
    }
    int chunk = bid % NC;
    int tile  = (bid / NC) % 16;
    int b     = bid / (NC * 16);
    int n4 = tile * 1024 + tid * 4;
    const float* fb = feats + (size_t)b * CHN * NPIX + n4;
    int c0 = chunk * (CHN / NC);
    float m1[4] = {-INFINITY, -INFINITY, -INFINITY, -INFINITY};
    float m2[4] = {-INFINITY, -INFINITY, -INFINITY, -INFINITY};
    for (int cb = c0; cb < c0 + CHN / NC; cb += 8) {
        float4 xs[8];
#pragma unroll
        for (int u = 0; u < 8; ++u)
            xs[u] = *(const float4*)(fb + (size_t)(cb + u) * NPIX);
#pragma unroll
        for (int u = 0; u < 8; ++u) {
            float xv[4] = {xs[u].x, xs[u].y, xs[u].z, xs[u].w};
#pragma unroll
            for (int q = 0; q < 4; ++q) {
                float val = xv[q];
                if (val > m1[q]) { m2[q] = m1[q]; m1[q] = val; }
                else if (val > m2[q]) m2[q] = val;
            }
        }
    }
    float2* po = part + (((size_t)(b * NC + chunk)) << 14) + n4;
#pragma unroll
    for (int q = 0; q < 4; ++q) po[q] = make_float2(m1[q], m2[q]);
}

// phase 2 merge; block 512 instead builds the plan (counts written by the
// previous dispatch -> in-stream visibility, same as round-0 k_hist->k_plan).
template <int NC>
__global__ __launch_bounds__(256) void k_cert2p(const float2* __restrict__ part,
                                                const int* __restrict__ counts,
                                                float* __restrict__ cert,
                                                int* __restrict__ plan) {
    int tid = threadIdx.x;
    if (blockIdx.x == 512) {
        __shared__ int c[128];
        __shared__ int sc[128];
        __shared__ int mn[128];
        __shared__ int present[NCLS];
        int* chan = plan + 4;
        int* pimg = plan + 20;
        int* pcls = plan + 148;
        int* pmap = plan + 276;
        int* Lp   = plan + 404;
        if (tid < 128) c[tid] = counts[tid];
        if (tid < NCLS) present[tid] = 0;
        __syncthreads();
        int e = 0;
        if (tid < 128) {
            if (c[tid] > 0) atomicOr(&present[tid & 15], 1);
            e = (c[tid] >= MAXV) ? 1 : 0;
            sc[tid] = e;
            mn[tid] = e ? c[tid] : 0x7fffffff;
        }
        __syncthreads();
        for (int off = 1; off < 128; off <<= 1) {
            int add = 0;
            if (tid < 128 && tid >= off) add = sc[tid - off];
            __syncthreads();
            if (tid < 128) sc[tid] += add;
            __syncthreads();
        }
        for (int s = 64; s > 0; s >>= 1) {
            if (tid < s) mn[tid] = min(mn[tid], mn[tid + s]);
            __syncthreads();
        }
        if (tid < 128) {
            pmap[tid] = e ? (sc[tid] - 1) : -1;
            if (e) {
                int p = sc[tid] - 1;
                pimg[p] = tid >> 4; pcls[p] = tid & 15; Lp[p] = c[tid];
            }
        }
        if (tid == 0) {
            int D = 0;
            for (int v = 0; v < NCLS; ++v) if (present[v]) chan[D++] = v;
            int nview = mn[0];
            plan[0] = nview; plan[1] = nview / 2; plan[2] = sc[127]; plan[3] = D;
        }
        return;
    }
    int t = blockIdx.x * 256 + tid;
    int b = t >> 14, pix = t & (NPIX - 1);
    float2 pm[NC];
#pragma unroll
    for (int j = 0; j < NC; ++j)
        pm[j] = part[(((size_t)(b * NC + j)) << 14) + pix];
    float m1 = -INFINITY, m2 = -INFINITY;
#pragma unroll
    for (int j = 0; j < NC; ++j) {
        if (pm[j].x > m1) { m2 = fmaxf(m1, pm[j].y); m1 = pm[j].x; }
        else              { m2 = fmaxf(m2, pm[j].x); }
    }
    cert[t] = m1 - m2;
}

// per-(b,v) radix-select the kv-th largest 64-bit key -> threshold
__global__ __launch_bounds__(512) void k_sel(const int* __restrict__ predict,
                                             const float* __restrict__ cert,
                                             const int* __restrict__ plan,
                                             ull* __restrict__ thrKey) {
    __shared__ ull keys[SORTN];
    __shared__ int whist[8][256];
    __shared__ int scan[257];
    __shared__ int wtot[4];
    __shared__ int lcnt;
    __shared__ ull sprefix;
    __shared__ int sremain;
    __shared__ int sdone;
    int tid = threadIdx.x;
    int lane = tid & 63, wv = tid >> 6;
    int b = blockIdx.x >> 4, v = blockIdx.x & 15;
    const int* pmap = plan + 276;
    int p = pmap[b * NCLS + v];
    if (p < 0) return;
    if (tid == 0) { lcnt = 0; sprefix = 0; sdone = 0; }
    __syncthreads();
    for (int n = tid; n < NPIX; n += 512) {
        bool match = (predict[b * NPIX + n] == v);
        ull mask = __ballot(match);
        if (mask) {
            int leader = __ffsll((long long)mask) - 1;
            int basepos = 0;
            if (lane == leader) basepos = atomicAdd(&lcnt, __popcll(mask));
            basepos = __shfl(basepos, leader, 64);
            if (match) {
                int pos = basepos + __popcll(mask & ((1ull << lane) - 1));
                if (pos < SORTN) {
                    unsigned int m = __float_as_uint(cert[b * NPIX + n]) | 0x80000000u;
                    keys[pos] = ((ull)m << 32) | (ull)(0xFFFFFFFFu - (unsigned)n);
                }
            }
        }
    }
    __syncthreads();
    int L = lcnt < SORTN ? lcnt : SORTN;
    int kv = plan[1] < L ? plan[1] : L;
    if (tid == 0) sremain = kv;
    __syncthreads();
    for (int shift = 56; shift >= 0; shift -= 8) {
        if (sdone) break;
        for (int i = tid; i < 8 * 256; i += 512) ((int*)whist)[i] = 0;
        ull pref = sprefix;
        int rem = sremain;
        __syncthreads();
        ull maskHi = (shift == 56) ? 0ULL : (~0ULL) << (shift + 8);
        for (int i = tid; i < L; i += 512) {
            ull kk = keys[i];
            if ((kk & maskHi) == pref)
                atomicAdd(&whist[wv][(int)((kk >> shift) & 255)], 1);
        }
        __syncthreads();
        int s = 0;
        if (tid < 256) {
            for (int w = 0; w < 8; ++w) s += whist[w][tid];
            for (int off = 1; off < 64; off <<= 1) {
                int o = __shfl_down(s, off, 64);
                if (lane + off < 64) s += o;
            }
            if (lane == 0) wtot[wv] = s;
        }
        __syncthreads();
        if (tid < 256) {
            int offs = 0;
            for (int w2 = wv + 1; w2 < 4; ++w2) offs += wtot[w2];
            s += offs;
            scan[tid] = s;
            if (tid == 0) scan[256] = 0;
        }
        __syncthreads();
        if (tid < 256) {
            int nxt = scan[tid + 1];
            if (s >= rem && nxt < rem) {
                sprefix = pref | ((ull)tid << shift);
                sremain = rem - nxt;
                if (s == rem) sdone = 1;
            }
        }
        __syncthreads();
    }
    if (tid == 0) thrKey[p] = sprefix;
}

// coalesced sweep accumulation; pos_sum is the UNNORMALIZED mean (cosines are
// scale-invariant). D==16 fast path batches the 16 plane loads.
__global__ __launch_bounds__(512) void k_accum(const float* __restrict__ feats,
                                               const int* __restrict__ predict,
                                               const float* __restrict__ cert,
                                               const int* __restrict__ plan,
                                               const ull* __restrict__ thrKey,
                                               float* __restrict__ pos_sum) {
    __shared__ float gacc[NCLS * 16];
    int tid = threadIdx.x;
    int t = blockIdx.x * 512 + tid;
    int b = (blockIdx.x * 512) >> 14;
    int n = t & (NPIX - 1);
    const int* chan = plan + 4;
    const int* pmap = plan + 276;
    int D = plan[3];
    if (tid < NCLS * 16) gacc[tid] = 0.f;
    __syncthreads();
    int v = predict[t];
    if (v >= 0 && v < NCLS) {
        int p = pmap[b * NCLS + v];
        if (p >= 0) {
            unsigned int m = __float_as_uint(cert[t]) | 0x80000000u;
            ull key = ((ull)m << 32) | (ull)(0xFFFFFFFFu - (unsigned)n);
            if (key >= thrKey[p]) {
                const float* fb = feats + ((size_t)(b * CHN) << 14) + n;
                if (D == 16) {
                    float x[16];
#pragma unroll
                    for (int d = 0; d < 16; ++d)
                        x[d] = fb[(size_t)chan[d] << 14];
#pragma unroll
                    for (int d = 0; d < 16; ++d)
                        atomicAdd(&gacc[v * 16 + d], x[d]);
                } else {
                    for (int d = 0; d < D; ++d)
                        atomicAdd(&gacc[v * 16 + d], fb[(size_t)chan[d] << 14]);
                }
            }
        }
    }
    __syncthreads();
    if (tid < NCLS * 16) {
        int p = pmap[b * NCLS + (tid >> 4)];
        if (p >= 0 && gacc[tid] != 0.f) atomicAdd(&pos_sum[p * 16 + (tid & 15)], gacc[tid]);
    }
}

__global__ __launch_bounds__(256) void k_intra(const int* __restrict__ plan,
                                               const float* __restrict__ pos_,
                                               float* __restrict__ posnorm,
                                               double* __restrict__ acc) {
    __shared__ float ppd[128 * 16];
    __shared__ float nr[128];
    __shared__ int cl[128];
    __shared__ double red[256];
    int tid = threadIdx.x;
    int P = plan[2], D = plan[3];
    const int* pcls = plan + 148;
    for (int i = tid; i < P * 16; i += 256) ppd[i] = pos_[i];
    __syncthreads();
    for (int p = tid; p < P; p += 256) {
        float s = 0;
        for (int d = 0; d < D; ++d) { float x = ppd[p * 16 + d]; s += x * x; }
        float nn = sqrtf(s);
        nr[p] = nn; posnorm[p] = nn; cl[p] = pcls[p];
    }
    __syncthreads();
    double num = 0; int cnt = 0;
    for (int idx = tid; idx < P * P; idx += 256) {
        int i = idx / P, j = idx - i * P;
        if (cl[i] != cl[j]) {
            float dot = 0;
            for (int d = 0; d < D; ++d) dot += ppd[i * 16 + d] * ppd[j * 16 + d];
            num += (double)(dot / (nr[i] * nr[j])) + 1.0;
            cnt++;
        }
    }
    red[tid] = num; __syncthreads();
    for (int s = 128; s > 0; s >>= 1) { if (tid < s) red[tid] += red[tid + s]; __syncthreads(); }
    double totnum = red[0]; __syncthreads();
    red[tid] = (double)cnt; __syncthreads();
    for (int s = 128; s > 0; s >>= 1) { if (tid < s) red[tid] += red[tid + s]; __syncthreads(); }
    if (tid == 0) atomicAdd(acc, totnum / red[0]);
}

__global__ __launch_bounds__(256) void k_inter(const float* __restrict__ feats,
                                               const int* __restrict__ predict,
                                               const int* __restrict__ plan,
                                               const float* __restrict__ pos_,
                                               const float* __restrict__ posnorm,
                                               double* __restrict__ acc) {
    __shared__ double red[256];
    int tid = threadIdx.x;
    int t = blockIdx.x * 256 + tid;
    int b = t >> 14, n = t & (NPIX - 1);
    int P = plan[2], D = plan[3];
    const int* chan = plan + 4;
    const int* pmap = plan + 276;
    const int* Lp = plan + 404;
    double term = 0;
    int v = predict[t];
    if (v >= 0 && v < NCLS) {
        int p = pmap[b * NCLS + v];
        if (p >= 0) {
            const float* fb = feats + ((size_t)(b * CHN) << 14) + n;
            float dot = 0, nv = 0;
            if (D == 16) {
                float x[16];
#pragma unroll
                for (int d = 0; d < 16; ++d) x[d] = fb[(size_t)chan[d] << 14];
#pragma unroll
                for (int d = 0; d < 16; ++d) {
                    float y = pos_[p * 16 + d];
                    dot += x[d] * y; nv += x[d] * x[d];
                }
            } else {
                for (int d = 0; d < D; ++d) {
                    float x = fb[(size_t)chan[d] << 14];
                    float y = pos_[p * 16 + d];
                    dot += x * y; nv += x * x;
                }
            }
            float den = fmaxf(sqrtf(nv) * posnorm[p], 1e-8f);
            term = (1.0 - (double)(dot / den)) / ((double)Lp[p] * (double)P);
        }
    }
    red[tid] = term; __syncthreads();
    for (int s = 128; s > 0; s >>= 1) { if (tid < s) red[tid] += red[tid + s]; __syncthreads(); }
    if (tid == 0) atomicAdd(acc, red[0]);
}

__global__ void k_finish(const double* __restrict__ acc, float* __restrict__ out) {
    out[0] = (float)acc[0];
}

// fallback single-phase cert (only if ws is too small for partials)
__global__ __launch_bounds__(256) void k_cert_direct(const float* __restrict__ feats,
                                                     float* __restrict__ cert) {
    int t = blockIdx.x * 256 + threadIdx.x;
    int b = t >> 12;
    int n4 = (t & 4095) * 4;
    const float* fb = feats + (size_t)b * CHN * NPIX + n4;
    float m1[4] = {-INFINITY, -INFINITY, -INFINITY, -INFINITY};
    float m2[4] = {-INFINITY, -INFINITY, -INFINITY, -INFINITY};
    for (int cb = 0; cb < CHN; cb += 8) {
        float4 xs[8];
#pragma unroll
        for (int u = 0; u < 8; ++u)
            xs[u] = *(const float4*)(fb + (size_t)(cb + u) * NPIX);
#pragma unroll
        for (int u = 0; u < 8; ++u) {
            float xv[4] = {xs[u].x, xs[u].y, xs[u].z, xs[u].w};
#pragma unroll
            for (int q = 0; q < 4; ++q) {
                float val = xv[q];
                if (val > m1[q]) { m2[q] = m1[q]; m1[q] = val; }
                else if (val > m2[q]) m2[q] = val;
            }
        }
    }
    float4 o = {m1[0] - m2[0], m1[1] - m2[1], m1[2] - m2[2], m1[3] - m2[3]};
    *(float4*)(cert + b * NPIX + n4) = o;
}

extern "C" void kernel_launch(void* const* d_in, const int* in_sizes, int n_in,
                              void* d_out, int out_size, void* d_ws, size_t ws_size,
                              hipStream_t stream) {
    const float* feats  = (const float*)d_in[0];
    const int* predict  = (const int*)d_in[2];
    char* ws = (char*)d_ws;
    double* acc     = (double*)ws;
    int* counts     = (int*)(ws + 64);
    int* plan       = (int*)(ws + 1024);
    ull* thrKey     = (ull*)(ws + 4096);
    float* pos_sum  = (float*)(ws + 8192);
    float* posnorm  = (float*)(ws + 16384);
    float* cert     = (float*)(ws + 32768);
    float2* part    = (float2*)(ws + 1048576);
    float* out      = (float*)d_out;

    hipMemsetAsync(ws, 0, 16384, stream);
    size_t need8 = 1048576 + (size_t)8 * BB * NPIX * sizeof(float2);
    size_t need4 = 1048576 + (size_t)4 * BB * NPIX * sizeof(float2);
    if (ws_size >= need8) {
        k_cert1h<8> <<<BB * 16 * 8, 256, 0, stream>>>(feats, predict, part, counts);
        k_cert2p<8> <<<513, 256, 0, stream>>>(part, counts, cert, plan);
    } else if (ws_size >= need4) {
        k_cert1h<4> <<<BB * 16 * 4, 256, 0, stream>>>(feats, predict, part, counts);
        k_cert2p<4> <<<513, 256, 0, stream>>>(part, counts, cert, plan);
    } else {
        k_hist <<<512, 256, 0, stream>>>(predict, counts);
        k_cert_direct <<<128, 256, 0, stream>>>(feats, cert);
        k_plan <<<1, 256, 0, stream>>>(counts, plan);
    }
    k_sel   <<<128, 512, 0, stream>>>(predict, cert, plan, thrKey);
    k_accum <<<256, 512, 0, stream>>>(feats, predict, cert, plan, thrKey, pos_sum);
    k_intra <<<1,   256, 0, stream>>>(plan, pos_sum, posnorm, acc);
    k_inter <<<512, 256, 0, stream>>>(feats, predict, plan, pos_sum, posnorm, acc);
    k_finish<<<1,   1,   0, stream>>>(acc, out);
}

// Round 3
// 260.727 us; speedup vs baseline: 1.2371x; 1.0268x over previous
//
#include <hip/hip_runtime.h>
#include <math.h>

#define BB 8
#define NCLS 16
#define NPIX 16384
#define CHN 256
#define MAXV 200
#define SORTN 2048

typedef unsigned long long ull;

// ---------------- ws layout (bytes) ----------------
// 0       : double accpart[513]   (plain stores by k_inter blocks; no zero needed)
// 8192    : int plan[536]: [0]=n_view [1]=k [2]=P [3]=D,
//           chan[16]@+4, pimg[128]@+20, pcls[128]@+148, pmap[128]@+276, Lp[128]@+404
// 12288   : ull thrKey[128]       (all p<P written by k_sel every launch)
// 16384   : float pos_sum[2048]   (zeroed by k_sel block 0, prior dispatch)
// 24576   : int counts2[512*16]   (plain per-block stores; every slot written)
// 65536   : float cert[131072]    (512 KB, fully overwritten)
// 1048576 : float2 part[NC*8*16384]
//
// Round-1 lesson: NO __threadfence / last-block-done fusion (device-scope
// fences on 8-XCD MI355X cost ~50 us aggregate in L2 writeback). All
// cross-kernel ordering uses in-stream dispatch boundaries.
// Round-3 change: zero-initialization-free ws -> no memset dispatch;
// intra folded into inter's block 512; 6 dispatches total.

// plan build from per-block histograms (device helper; one block, >=128 thr)
__device__ __forceinline__ void build_plan(const int* __restrict__ counts2,
                                           int* __restrict__ plan, int tid) {
    __shared__ int c[128];
    __shared__ int sc[128];
    __shared__ int mn[128];
    __shared__ int present[NCLS];
    int* chan = plan + 4;
    int* pimg = plan + 20;
    int* pcls = plan + 148;
    int* pmap = plan + 276;
    int* Lp   = plan + 404;
    if (tid < 128) {
        int b = tid >> 4, v = tid & 15;
        int s = 0;
        for (int j = 0; j < 64; ++j) s += counts2[((b << 6) + j) * NCLS + v];
        c[tid] = s;
    }
    if (tid < NCLS) present[tid] = 0;
    __syncthreads();
    int e = 0;
    if (tid < 128) {
        if (c[tid] > 0) atomicOr(&present[tid & 15], 1);
        e = (c[tid] >= MAXV) ? 1 : 0;
        sc[tid] = e;
        mn[tid] = e ? c[tid] : 0x7fffffff;
    }
    __syncthreads();
    for (int off = 1; off < 128; off <<= 1) {
        int add = 0;
        if (tid < 128 && tid >= off) add = sc[tid - off];
        __syncthreads();
        if (tid < 128) sc[tid] += add;
        __syncthreads();
    }
    for (int s = 64; s > 0; s >>= 1) {
        if (tid < s) mn[tid] = min(mn[tid], mn[tid + s]);
        __syncthreads();
    }
    if (tid < 128) {
        pmap[tid] = e ? (sc[tid] - 1) : -1;
        if (e) {
            int p = sc[tid] - 1;
            pimg[p] = tid >> 4; pcls[p] = tid & 15; Lp[p] = c[tid];
        }
    }
    if (tid == 0) {
        int D = 0;
        for (int v = 0; v < NCLS; ++v) if (present[v]) chan[D++] = v;
        int nview = mn[0];
        plan[0] = nview; plan[1] = nview / 2; plan[2] = sc[127]; plan[3] = D;
    }
}

// phase 1: 8-deep float4 load batching. Blocks 0..511 also histogram a
// 256-entry predict slice into counts2 via PLAIN stores (no zero needed).
template <int NC>
__global__ __launch_bounds__(256) void k_cert1h(const float* __restrict__ feats,
                                                const int* __restrict__ predict,
                                                float2* __restrict__ part,
                                                int* __restrict__ counts2) {
    int bid = blockIdx.x;                  // BB * 16 * NC blocks (>= 512)
    int tid = threadIdx.x;
    if (bid < 512) {
        __shared__ int h[NCLS];
        if (tid < NCLS) h[tid] = 0;
        __syncthreads();
        int v = predict[bid * 256 + tid];
        if (v >= 0 && v < NCLS) atomicAdd(&h[v], 1);
        __syncthreads();
        if (tid < NCLS) counts2[bid * NCLS + tid] = h[tid];
    }
    int chunk = bid % NC;
    int tile  = (bid / NC) % 16;
    int b     = bid / (NC * 16);
    int n4 = tile * 1024 + tid * 4;
    const float* fb = feats + (size_t)b * CHN * NPIX + n4;
    int c0 = chunk * (CHN / NC);
    float m1[4] = {-INFINITY, -INFINITY, -INFINITY, -INFINITY};
    float m2[4] = {-INFINITY, -INFINITY, -INFINITY, -INFINITY};
    for (int cb = c0; cb < c0 + CHN / NC; cb += 8) {
        float4 xs[8];
#pragma unroll
        for (int u = 0; u < 8; ++u)
            xs[u] = *(const float4*)(fb + (size_t)(cb + u) * NPIX);
#pragma unroll
        for (int u = 0; u < 8; ++u) {
            float xv[4] = {xs[u].x, xs[u].y, xs[u].z, xs[u].w};
#pragma unroll
            for (int q = 0; q < 4; ++q) {
                float val = xv[q];
                if (val > m1[q]) { m2[q] = m1[q]; m1[q] = val; }
                else if (val > m2[q]) m2[q] = val;
            }
        }
    }
    float2* po = part + (((size_t)(b * NC + chunk)) << 14) + n4;
#pragma unroll
    for (int q = 0; q < 4; ++q) po[q] = make_float2(m1[q], m2[q]);
}

// phase 2 merge; block 512 builds the plan from counts2 (previous dispatch).
template <int NC>
__global__ __launch_bounds__(256) void k_cert2p(const float2* __restrict__ part,
                                                const int* __restrict__ counts2,
                                                float* __restrict__ cert,
                                                int* __restrict__ plan) {
    int tid = threadIdx.x;
    if (blockIdx.x == 512) {
        build_plan(counts2, plan, tid);
        return;
    }
    int t = blockIdx.x * 256 + tid;
    int b = t >> 14, pix = t & (NPIX - 1);
    float2 pm[NC];
#pragma unroll
    for (int j = 0; j < NC; ++j)
        pm[j] = part[(((size_t)(b * NC + j)) << 14) + pix];
    float m1 = -INFINITY, m2 = -INFINITY;
#pragma unroll
    for (int j = 0; j < NC; ++j) {
        if (pm[j].x > m1) { m2 = fmaxf(m1, pm[j].y); m1 = pm[j].x; }
        else              { m2 = fmaxf(m2, pm[j].x); }
    }
    cert[t] = m1 - m2;
}

// per-(b,v) radix-select the kv-th largest 64-bit key -> threshold.
// Block 0 additionally zeroes pos_sum (consumed by the NEXT dispatch).
__global__ __launch_bounds__(512) void k_sel(const int* __restrict__ predict,
                                             const float* __restrict__ cert,
                                             const int* __restrict__ plan,
                                             ull* __restrict__ thrKey,
                                             float* __restrict__ pos_sum) {
    __shared__ ull keys[SORTN];
    __shared__ int whist[8][256];
    __shared__ int scan[257];
    __shared__ int wtot[4];
    __shared__ int lcnt;
    __shared__ ull sprefix;
    __shared__ int sremain;
    __shared__ int sdone;
    int tid = threadIdx.x;
    if (blockIdx.x == 0) {
#pragma unroll
        for (int i = 0; i < 4; ++i) pos_sum[i * 512 + tid] = 0.f;
    }
    int lane = tid & 63, wv = tid >> 6;
    int b = blockIdx.x >> 4, v = blockIdx.x & 15;
    const int* pmap = plan + 276;
    int p = pmap[b * NCLS + v];
    if (p < 0) return;
    if (tid == 0) { lcnt = 0; sprefix = 0; sdone = 0; }
    __syncthreads();
    for (int n = tid; n < NPIX; n += 512) {
        bool match = (predict[b * NPIX + n] == v);
        ull mask = __ballot(match);
        if (mask) {
            int leader = __ffsll((long long)mask) - 1;
            int basepos = 0;
            if (lane == leader) basepos = atomicAdd(&lcnt, __popcll(mask));
            basepos = __shfl(basepos, leader, 64);
            if (match) {
                int pos = basepos + __popcll(mask & ((1ull << lane) - 1));
                if (pos < SORTN) {
                    unsigned int m = __float_as_uint(cert[b * NPIX + n]) | 0x80000000u;
                    keys[pos] = ((ull)m << 32) | (ull)(0xFFFFFFFFu - (unsigned)n);
                }
            }
        }
    }
    __syncthreads();
    int L = lcnt < SORTN ? lcnt : SORTN;
    int kv = plan[1] < L ? plan[1] : L;
    if (tid == 0) sremain = kv;
    __syncthreads();
    for (int shift = 56; shift >= 0; shift -= 8) {
        if (sdone) break;
        for (int i = tid; i < 8 * 256; i += 512) ((int*)whist)[i] = 0;
        ull pref = sprefix;
        int rem = sremain;
        __syncthreads();
        ull maskHi = (shift == 56) ? 0ULL : (~0ULL) << (shift + 8);
        for (int i = tid; i < L; i += 512) {
            ull kk = keys[i];
            if ((kk & maskHi) == pref)
                atomicAdd(&whist[wv][(int)((kk >> shift) & 255)], 1);
        }
        __syncthreads();
        int s = 0;
        if (tid < 256) {
            for (int w = 0; w < 8; ++w) s += whist[w][tid];
            for (int off = 1; off < 64; off <<= 1) {
                int o = __shfl_down(s, off, 64);
                if (lane + off < 64) s += o;
            }
            if (lane == 0) wtot[wv] = s;
        }
        __syncthreads();
        if (tid < 256) {
            int offs = 0;
            for (int w2 = wv + 1; w2 < 4; ++w2) offs += wtot[w2];
            s += offs;
            scan[tid] = s;
            if (tid == 0) scan[256] = 0;
        }
        __syncthreads();
        if (tid < 256) {
            int nxt = scan[tid + 1];
            if (s >= rem && nxt < rem) {
                sprefix = pref | ((ull)tid << shift);
                sremain = rem - nxt;
                if (s == rem) sdone = 1;
            }
        }
        __syncthreads();
    }
    if (tid == 0) thrKey[p] = sprefix;
}

// coalesced sweep accumulation; pos_sum is the UNNORMALIZED mean (cosines are
// scale-invariant). D==16 fast path batches the 16 plane loads.
__global__ __launch_bounds__(512) void k_accum(const float* __restrict__ feats,
                                               const int* __restrict__ predict,
                                               const float* __restrict__ cert,
                                               const int* __restrict__ plan,
                                               const ull* __restrict__ thrKey,
                                               float* __restrict__ pos_sum) {
    __shared__ float gacc[NCLS * 16];
    int tid = threadIdx.x;
    int t = blockIdx.x * 512 + tid;
    int b = (blockIdx.x * 512) >> 14;
    int n = t & (NPIX - 1);
    const int* chan = plan + 4;
    const int* pmap = plan + 276;
    int D = plan[3];
    if (tid < NCLS * 16) gacc[tid] = 0.f;
    __syncthreads();
    int v = predict[t];
    if (v >= 0 && v < NCLS) {
        int p = pmap[b * NCLS + v];
        if (p >= 0) {
            unsigned int m = __float_as_uint(cert[t]) | 0x80000000u;
            ull key = ((ull)m << 32) | (ull)(0xFFFFFFFFu - (unsigned)n);
            if (key >= thrKey[p]) {
                const float* fb = feats + ((size_t)(b * CHN) << 14) + n;
                if (D == 16) {
                    float x[16];
#pragma unroll
                    for (int d = 0; d < 16; ++d)
                        x[d] = fb[(size_t)chan[d] << 14];
#pragma unroll
                    for (int d = 0; d < 16; ++d)
                        atomicAdd(&gacc[v * 16 + d], x[d]);
                } else {
                    for (int d = 0; d < D; ++d)
                        atomicAdd(&gacc[v * 16 + d], fb[(size_t)chan[d] << 14]);
                }
            }
        }
    }
    __syncthreads();
    if (tid < NCLS * 16) {
        int p = pmap[b * NCLS + (tid >> 4)];
        if (p >= 0 && gacc[tid] != 0.f) atomicAdd(&pos_sum[p * 16 + (tid & 15)], gacc[tid]);
    }
}

// inter loss (blocks 0..511) + intra loss (block 512). Each block computes the
// 128 pos-norms locally from the tiny L2-resident pos_sum (removes the
// serialized posnorm producer). Per-block partials -> accpart (plain stores).
__global__ __launch_bounds__(256) void k_interintra(const float* __restrict__ feats,
                                                    const int* __restrict__ predict,
                                                    const int* __restrict__ plan,
                                                    const float* __restrict__ pos_sum,
                                                    double* __restrict__ accpart) {
    __shared__ float ppd[128 * 16];
    __shared__ float nr[128];
    __shared__ double red[256];
    int tid = threadIdx.x;
    int P = plan[2], D = plan[3];
    const int* pcls = plan + 148;
    for (int i = tid; i < P * 16; i += 256) ppd[i] = pos_sum[i];
    __syncthreads();
    for (int p = tid; p < P; p += 256) {
        float s = 0;
        for (int d = 0; d < D; ++d) { float x = ppd[p * 16 + d]; s += x * x; }
        nr[p] = sqrtf(s);
    }
    __syncthreads();

    if (blockIdx.x == 512) {
        // ---------------- intra loss ----------------
        __shared__ int cl[128];
        for (int p = tid; p < P; p += 256) cl[p] = pcls[p];
        __syncthreads();
        double num = 0; int cnt = 0;
        for (int idx = tid; idx < P * P; idx += 256) {
            int i = idx / P, j = idx - i * P;
            if (cl[i] != cl[j]) {
                float dot = 0;
                for (int d = 0; d < D; ++d) dot += ppd[i * 16 + d] * ppd[j * 16 + d];
                num += (double)(dot / (nr[i] * nr[j])) + 1.0;
                cnt++;
            }
        }
        red[tid] = num; __syncthreads();
        for (int s = 128; s > 0; s >>= 1) { if (tid < s) red[tid] += red[tid + s]; __syncthreads(); }
        double totnum = red[0]; __syncthreads();
        red[tid] = (double)cnt; __syncthreads();
        for (int s = 128; s > 0; s >>= 1) { if (tid < s) red[tid] += red[tid + s]; __syncthreads(); }
        if (tid == 0) accpart[512] = totnum / red[0];
        return;
    }

    // ---------------- inter loss ----------------
    int t = blockIdx.x * 256 + tid;
    int b = t >> 14, n = t & (NPIX - 1);
    const int* chan = plan + 4;
    const int* pmap = plan + 276;
    const int* Lp = plan + 404;
    double term = 0;
    int v = predict[t];
    if (v >= 0 && v < NCLS) {
        int p = pmap[b * NCLS + v];
        if (p >= 0) {
            const float* fb = feats + ((size_t)(b * CHN) << 14) + n;
            float dot = 0, nv = 0;
            if (D == 16) {
                float x[16];
#pragma unroll
                for (int d = 0; d < 16; ++d) x[d] = fb[(size_t)chan[d] << 14];
#pragma unroll
                for (int d = 0; d < 16; ++d) {
                    float y = ppd[p * 16 + d];
                    dot += x[d] * y; nv += x[d] * x[d];
                }
            } else {
                for (int d = 0; d < D; ++d) {
                    float x = fb[(size_t)chan[d] << 14];
                    float y = ppd[p * 16 + d];
                    dot += x * y; nv += x * x;
                }
            }
            float den = fmaxf(sqrtf(nv) * nr[p], 1e-8f);
            term = (1.0 - (double)(dot / den)) / ((double)Lp[p] * (double)P);
        }
    }
    red[tid] = term; __syncthreads();
    for (int s = 128; s > 0; s >>= 1) { if (tid < s) red[tid] += red[tid + s]; __syncthreads(); }
    if (tid == 0) accpart[blockIdx.x] = red[0];
}

__global__ __launch_bounds__(256) void k_finish(const double* __restrict__ accpart,
                                                float* __restrict__ out) {
    __shared__ double red[256];
    int tid = threadIdx.x;
    double s = 0;
    for (int i = tid; i < 513; i += 256) s += accpart[i];
    red[tid] = s; __syncthreads();
    for (int st = 128; st > 0; st >>= 1) { if (tid < st) red[tid] += red[tid + st]; __syncthreads(); }
    if (tid == 0) out[0] = (float)red[0];
}

// ---- fallback path (ws too small for partials) ----
__global__ __launch_bounds__(256) void k_hist(const int* __restrict__ predict,
                                              int* __restrict__ counts2) {
    __shared__ int h[NCLS];
    int tid = threadIdx.x;
    if (tid < NCLS) h[tid] = 0;
    __syncthreads();
    int v = predict[blockIdx.x * 256 + tid];
    if (v >= 0 && v < NCLS) atomicAdd(&h[v], 1);
    __syncthreads();
    if (tid < NCLS) counts2[blockIdx.x * NCLS + tid] = h[tid];
}

__global__ __launch_bounds__(256) void k_plan1(const int* __restrict__ counts2,
                                               int* __restrict__ plan) {
    build_plan(counts2, plan, threadIdx.x);
}

__global__ __launch_bounds__(256) void k_cert_direct(const float* __restrict__ feats,
                                                     float* __restrict__ cert) {
    int t = blockIdx.x * 256 + threadIdx.x;
    int b = t >> 12;
    int n4 = (t & 4095) * 4;
    const float* fb = feats + (size_t)b * CHN * NPIX + n4;
    float m1[4] = {-INFINITY, -INFINITY, -INFINITY, -INFINITY};
    float m2[4] = {-INFINITY, -INFINITY, -INFINITY, -INFINITY};
    for (int cb = 0; cb < CHN; cb += 8) {
        float4 xs[8];
#pragma unroll
        for (int u = 0; u < 8; ++u)
            xs[u] = *(const float4*)(fb + (size_t)(cb + u) * NPIX);
#pragma unroll
        for (int u = 0; u < 8; ++u) {
            float xv[4] = {xs[u].x, xs[u].y, xs[u].z, xs[u].w};
#pragma unroll
            for (int q = 0; q < 4; ++q) {
                float val = xv[q];
                if (val > m1[q]) { m2[q] = m1[q]; m1[q] = val; }
                else if (val > m2[q]) m2[q] = val;
            }
        }
    }
    float4 o = {m1[0] - m2[0], m1[1] - m2[1], m1[2] - m2[2], m1[3] - m2[3]};
    *(float4*)(cert + b * NPIX + n4) = o;
}

extern "C" void kernel_launch(void* const* d_in, const int* in_sizes, int n_in,
                              void* d_out, int out_size, void* d_ws, size_t ws_size,
                              hipStream_t stream) {
    const float* feats  = (const float*)d_in[0];
    const int* predict  = (const int*)d_in[2];
    char* ws = (char*)d_ws;
    double* accpart = (double*)ws;
    int* plan       = (int*)(ws + 8192);
    ull* thrKey     = (ull*)(ws + 12288);
    float* pos_sum  = (float*)(ws + 16384);
    int* counts2    = (int*)(ws + 24576);
    float* cert     = (float*)(ws + 65536);
    float2* part    = (float2*)(ws + 1048576);
    float* out      = (float*)d_out;

    size_t need8 = 1048576 + (size_t)8 * BB * NPIX * sizeof(float2);
    size_t need4 = 1048576 + (size_t)4 * BB * NPIX * sizeof(float2);
    if (ws_size >= need8) {
        k_cert1h<8> <<<BB * 16 * 8, 256, 0, stream>>>(feats, predict, part, counts2);
        k_cert2p<8> <<<513, 256, 0, stream>>>(part, counts2, cert, plan);
    } else if (ws_size >= need4) {
        k_cert1h<4> <<<BB * 16 * 4, 256, 0, stream>>>(feats, predict, part, counts2);
        k_cert2p<4> <<<513, 256, 0, stream>>>(part, counts2, cert, plan);
    } else {
        k_hist <<<512, 256, 0, stream>>>(predict, counts2);
        k_cert_direct <<<128, 256, 0, stream>>>(feats, cert);
        k_plan1 <<<1, 256, 0, stream>>>(counts2, plan);
    }
    k_sel        <<<128, 512, 0, stream>>>(predict, cert, plan, thrKey, pos_sum);
    k_accum      <<<256, 512, 0, stream>>>(feats, predict, cert, plan, thrKey, pos_sum);
    k_interintra <<<513, 256, 0, stream>>>(feats, predict, plan, pos_sum, accpart);
    k_finish     <<<1,   256, 0, stream>>>(accpart, out);
}

// Round 4
// 256.335 us; speedup vs baseline: 1.2583x; 1.0171x over previous
//
#include <hip/hip_runtime.h>
#include <math.h>

#define BB 8
#define NCLS 16
#define NPIX 16384
#define CHN 256
#define MAXV 200
#define SORTN 2048

typedef unsigned long long ull;

// ---------------- ws layout (bytes) ----------------
// 0       : double accpart[513]   (plain stores by k_interintra; no zero needed)
// 8192    : int plan[536]: [0]=n_view [1]=k [2]=P [3]=D,
//           chan[16]@+4, pimg[128]@+20, pcls[128]@+148, pmap[128]@+276, Lp[128]@+404
// 12288   : ull thrKey[128]       (all p<P written by k_sel every launch)
// 16384   : float pos_sum[2048]   (zeroed by k_sel block 128, prior dispatch)
// 24576   : int counts2[512*16]   (plain per-block stores; every slot written)
// 65536   : float cert[131072]    (512 KB, fully overwritten)
// total need ~= 590 KB
//
// Round-1 lesson: NO __threadfence / last-block-done fusion (device-scope
// fences on 8-XCD MI355X cost ~50 us aggregate in L2 writeback). All
// cross-kernel ordering uses in-stream dispatch boundaries.
// Round-4 change: single-phase cert (no partials round-trip), k_sel blocks
// derive (p,kv) locally from counts2; block 128 of k_sel writes the canonical
// plan for downstream dispatches. 5 dispatches total.

// plan build from per-block histograms (device helper; one block, >=128 thr)
__device__ __forceinline__ void build_plan(const int* __restrict__ counts2,
                                           int* __restrict__ plan, int tid) {
    __shared__ int c[128];
    __shared__ int sc[128];
    __shared__ int mn[128];
    __shared__ int present[NCLS];
    int* chan = plan + 4;
    int* pimg = plan + 20;
    int* pcls = plan + 148;
    int* pmap = plan + 276;
    int* Lp   = plan + 404;
    if (tid < 128) {
        int b = tid >> 4, v = tid & 15;
        int s = 0;
        for (int j = 0; j < 64; ++j) s += counts2[((b << 6) + j) * NCLS + v];
        c[tid] = s;
    }
    if (tid < NCLS) present[tid] = 0;
    __syncthreads();
    int e = 0;
    if (tid < 128) {
        if (c[tid] > 0) atomicOr(&present[tid & 15], 1);
        e = (c[tid] >= MAXV) ? 1 : 0;
        sc[tid] = e;
        mn[tid] = e ? c[tid] : 0x7fffffff;
    }
    __syncthreads();
    for (int off = 1; off < 128; off <<= 1) {
        int add = 0;
        if (tid < 128 && tid >= off) add = sc[tid - off];
        __syncthreads();
        if (tid < 128) sc[tid] += add;
        __syncthreads();
    }
    for (int s = 64; s > 0; s >>= 1) {
        if (tid < s) mn[tid] = min(mn[tid], mn[tid + s]);
        __syncthreads();
    }
    if (tid < 128) {
        pmap[tid] = e ? (sc[tid] - 1) : -1;
        if (e) {
            int p = sc[tid] - 1;
            pimg[p] = tid >> 4; pcls[p] = tid & 15; Lp[p] = c[tid];
        }
    }
    if (tid == 0) {
        int D = 0;
        for (int v = 0; v < NCLS; ++v) if (present[v]) chan[D++] = v;
        int nview = mn[0];
        plan[0] = nview; plan[1] = nview / 2; plan[2] = sc[127]; plan[3] = D;
    }
}

// single-phase top-2 certainty + predict histogram. One block owns 256 pixels
// x all 256 channels: 4 channel-slices of 64, merged through LDS. 8-deep
// float4 load batching (16B/lane, wave-contiguous 1KB transactions).
// Hist: plain per-block stores into counts2 (no zeroing needed anywhere).
__global__ __launch_bounds__(256) void k_cert(const float* __restrict__ feats,
                                              const int* __restrict__ predict,
                                              float* __restrict__ cert,
                                              int* __restrict__ counts2) {
    __shared__ int h[NCLS];
    __shared__ float2 sh[4 * 256];
    int bid = blockIdx.x;          // 512 blocks
    int tid = threadIdx.x;
    if (tid < NCLS) h[tid] = 0;
    __syncthreads();
    int pv = predict[bid * 256 + tid];
    if (pv >= 0 && pv < NCLS) atomicAdd(&h[pv], 1);

    int lane = tid & 63;           // pixel-quad index within the tile
    int slice = tid >> 6;          // channel slice 0..3
    int b = bid >> 6;              // 64 tiles per image
    int tile = bid & 63;
    int n4 = tile * 256 + lane * 4;
    const float* fb = feats + (size_t)b * CHN * NPIX + (size_t)(slice * 64) * NPIX + n4;
    float m1[4] = {-INFINITY, -INFINITY, -INFINITY, -INFINITY};
    float m2[4] = {-INFINITY, -INFINITY, -INFINITY, -INFINITY};
    for (int cb = 0; cb < 64; cb += 8) {
        float4 xs[8];
#pragma unroll
        for (int u = 0; u < 8; ++u)
            xs[u] = *(const float4*)(fb + (size_t)(cb + u) * NPIX);
#pragma unroll
        for (int u = 0; u < 8; ++u) {
            float xv[4] = {xs[u].x, xs[u].y, xs[u].z, xs[u].w};
#pragma unroll
            for (int q = 0; q < 4; ++q) {
                float val = xv[q];
                if (val > m1[q]) { m2[q] = m1[q]; m1[q] = val; }
                else if (val > m2[q]) m2[q] = val;
            }
        }
    }
#pragma unroll
    for (int q = 0; q < 4; ++q)
        sh[slice * 256 + lane * 4 + q] = make_float2(m1[q], m2[q]);
    __syncthreads();
    if (tid < NCLS) counts2[bid * NCLS + tid] = h[tid];
    float M1 = -INFINITY, M2 = -INFINITY;
#pragma unroll
    for (int j = 0; j < 4; ++j) {
        float2 pm = sh[j * 256 + tid];
        if (pm.x > M1) { M2 = fmaxf(M1, pm.y); M1 = pm.x; }
        else           { M2 = fmaxf(M2, pm.x); }
    }
    cert[bid * 256 + tid] = M1 - M2;
}

// per-(b,v) radix-select the kv-th largest 64-bit key -> threshold.
// Blocks 0..127 derive (p, kv) LOCALLY from counts2 (no plan dependency).
// Block 128 writes the canonical plan for downstream dispatches + zeroes
// pos_sum (consumed by the NEXT dispatch -> in-stream ordering, no fence).
__global__ __launch_bounds__(512) void k_sel(const int* __restrict__ predict,
                                             const float* __restrict__ cert,
                                             const int* __restrict__ counts2,
                                             int* __restrict__ plan,
                                             ull* __restrict__ thrKey,
                                             float* __restrict__ pos_sum) {
    int tid = threadIdx.x;
    int lane = tid & 63, wv = tid >> 6;
    if (blockIdx.x == 128) {
#pragma unroll
        for (int i = 0; i < 4; ++i) pos_sum[i * 512 + tid] = 0.f;
        build_plan(counts2, plan, tid);
        return;
    }
    // ---- local plan derivation (reads only counts2, written last dispatch)
    __shared__ int cc[128];
    __shared__ int mnl[128];
    __shared__ ull em[2];
    int cv = 0;
    if (tid < 128) {
        int b0 = tid >> 4, v0 = tid & 15;
        int s = 0;
        for (int j = 0; j < 64; ++j) s += counts2[((b0 << 6) + j) * NCLS + v0];
        cv = s; cc[tid] = s;
    }
    bool e = (tid < 128) && (cv >= MAXV);
    ull m = __ballot(e);
    if (lane == 0 && wv < 2) em[wv] = m;
    if (tid < 128) mnl[tid] = e ? cv : 0x7fffffff;
    __syncthreads();
    for (int s = 64; s > 0; s >>= 1) {
        if (tid < s) mnl[tid] = min(mnl[tid], mnl[tid + s]);
        __syncthreads();
    }
    int bvid = blockIdx.x;
    if (cc[bvid] < MAXV) return;               // uniform across block
    int kvplan = mnl[0] >> 1;                  // n_view / 2
    int p = (bvid < 64)
        ? __popcll(em[0] & ((1ull << bvid) - 1))
        : __popcll(em[0]) + __popcll(em[1] & ((1ull << (bvid - 64)) - 1));
    int b = bvid >> 4, v = bvid & 15;

    // ---- radix select (unchanged)
    __shared__ ull keys[SORTN];
    __shared__ int whist[8][256];
    __shared__ int scan[257];
    __shared__ int wtot[4];
    __shared__ int lcnt;
    __shared__ ull sprefix;
    __shared__ int sremain;
    __shared__ int sdone;
    if (tid == 0) { lcnt = 0; sprefix = 0; sdone = 0; }
    __syncthreads();
    for (int n = tid; n < NPIX; n += 512) {
        bool match = (predict[b * NPIX + n] == v);
        ull mask = __ballot(match);
        if (mask) {
            int leader = __ffsll((long long)mask) - 1;
            int basepos = 0;
            if (lane == leader) basepos = atomicAdd(&lcnt, __popcll(mask));
            basepos = __shfl(basepos, leader, 64);
            if (match) {
                int pos = basepos + __popcll(mask & ((1ull << lane) - 1));
                if (pos < SORTN) {
                    unsigned int mm = __float_as_uint(cert[b * NPIX + n]) | 0x80000000u;
                    keys[pos] = ((ull)mm << 32) | (ull)(0xFFFFFFFFu - (unsigned)n);
                }
            }
        }
    }
    __syncthreads();
    int L = lcnt < SORTN ? lcnt : SORTN;
    int kv = kvplan < L ? kvplan : L;
    if (tid == 0) sremain = kv;
    __syncthreads();
    for (int shift = 56; shift >= 0; shift -= 8) {
        if (sdone) break;
        for (int i = tid; i < 8 * 256; i += 512) ((int*)whist)[i] = 0;
        ull pref = sprefix;
        int rem = sremain;
        __syncthreads();
        ull maskHi = (shift == 56) ? 0ULL : (~0ULL) << (shift + 8);
        for (int i = tid; i < L; i += 512) {
            ull kk = keys[i];
            if ((kk & maskHi) == pref)
                atomicAdd(&whist[wv][(int)((kk >> shift) & 255)], 1);
        }
        __syncthreads();
        int s = 0;
        if (tid < 256) {
            for (int w = 0; w < 8; ++w) s += whist[w][tid];
            for (int off = 1; off < 64; off <<= 1) {
                int o = __shfl_down(s, off, 64);
                if (lane + off < 64) s += o;
            }
            if (lane == 0) wtot[wv] = s;
        }
        __syncthreads();
        if (tid < 256) {
            int offs = 0;
            for (int w2 = wv + 1; w2 < 4; ++w2) offs += wtot[w2];
            s += offs;
            scan[tid] = s;
            if (tid == 0) scan[256] = 0;
        }
        __syncthreads();
        if (tid < 256) {
            int nxt = scan[tid + 1];
            if (s >= rem && nxt < rem) {
                sprefix = pref | ((ull)tid << shift);
                sremain = rem - nxt;
                if (s == rem) sdone = 1;
            }
        }
        __syncthreads();
    }
    if (tid == 0) thrKey[p] = sprefix;
}

// coalesced sweep accumulation; pos_sum is the UNNORMALIZED mean (cosines are
// scale-invariant). D==16 fast path batches the 16 plane loads.
__global__ __launch_bounds__(512) void k_accum(const float* __restrict__ feats,
                                               const int* __restrict__ predict,
                                               const float* __restrict__ cert,
                                               const int* __restrict__ plan,
                                               const ull* __restrict__ thrKey,
                                               float* __restrict__ pos_sum) {
    __shared__ float gacc[NCLS * 16];
    int tid = threadIdx.x;
    int t = blockIdx.x * 512 + tid;
    int b = (blockIdx.x * 512) >> 14;
    int n = t & (NPIX - 1);
    const int* chan = plan + 4;
    const int* pmap = plan + 276;
    int D = plan[3];
    if (tid < NCLS * 16) gacc[tid] = 0.f;
    __syncthreads();
    int v = predict[t];
    if (v >= 0 && v < NCLS) {
        int p = pmap[b * NCLS + v];
        if (p >= 0) {
            unsigned int m = __float_as_uint(cert[t]) | 0x80000000u;
            ull key = ((ull)m << 32) | (ull)(0xFFFFFFFFu - (unsigned)n);
            if (key >= thrKey[p]) {
                const float* fb = feats + ((size_t)(b * CHN) << 14) + n;
                if (D == 16) {
                    float x[16];
#pragma unroll
                    for (int d = 0; d < 16; ++d)
                        x[d] = fb[(size_t)chan[d] << 14];
#pragma unroll
                    for (int d = 0; d < 16; ++d)
                        atomicAdd(&gacc[v * 16 + d], x[d]);
                } else {
                    for (int d = 0; d < D; ++d)
                        atomicAdd(&gacc[v * 16 + d], fb[(size_t)chan[d] << 14]);
                }
            }
        }
    }
    __syncthreads();
    if (tid < NCLS * 16) {
        int p = pmap[b * NCLS + (tid >> 4)];
        if (p >= 0 && gacc[tid] != 0.f) atomicAdd(&pos_sum[p * 16 + (tid & 15)], gacc[tid]);
    }
}

// inter loss (blocks 0..511) + intra loss (block 512). Each block computes the
// 128 pos-norms locally from the tiny L2-resident pos_sum. Per-block partials
// -> accpart (plain stores, no zero / no atomics / no fences).
__global__ __launch_bounds__(256) void k_interintra(const float* __restrict__ feats,
                                                    const int* __restrict__ predict,
                                                    const int* __restrict__ plan,
                                                    const float* __restrict__ pos_sum,
                                                    double* __restrict__ accpart) {
    __shared__ float ppd[128 * 16];
    __shared__ float nr[128];
    __shared__ double red[256];
    int tid = threadIdx.x;
    int P = plan[2], D = plan[3];
    const int* pcls = plan + 148;
    for (int i = tid; i < P * 16; i += 256) ppd[i] = pos_sum[i];
    __syncthreads();
    for (int p = tid; p < P; p += 256) {
        float s = 0;
        for (int d = 0; d < D; ++d) { float x = ppd[p * 16 + d]; s += x * x; }
        nr[p] = sqrtf(s);
    }
    __syncthreads();

    if (blockIdx.x == 512) {
        // ---------------- intra loss ----------------
        __shared__ int cl[128];
        for (int p = tid; p < P; p += 256) cl[p] = pcls[p];
        __syncthreads();
        double num = 0; int cnt = 0;
        for (int idx = tid; idx < P * P; idx += 256) {
            int i = idx / P, j = idx - i * P;
            if (cl[i] != cl[j]) {
                float dot = 0;
                for (int d = 0; d < D; ++d) dot += ppd[i * 16 + d] * ppd[j * 16 + d];
                num += (double)(dot / (nr[i] * nr[j])) + 1.0;
                cnt++;
            }
        }
        red[tid] = num; __syncthreads();
        for (int s = 128; s > 0; s >>= 1) { if (tid < s) red[tid] += red[tid + s]; __syncthreads(); }
        double totnum = red[0]; __syncthreads();
        red[tid] = (double)cnt; __syncthreads();
        for (int s = 128; s > 0; s >>= 1) { if (tid < s) red[tid] += red[tid + s]; __syncthreads(); }
        if (tid == 0) accpart[512] = totnum / red[0];
        return;
    }

    // ---------------- inter loss ----------------
    int t = blockIdx.x * 256 + tid;
    int b = t >> 14, n = t & (NPIX - 1);
    const int* chan = plan + 4;
    const int* pmap = plan + 276;
    const int* Lp = plan + 404;
    double term = 0;
    int v = predict[t];
    if (v >= 0 && v < NCLS) {
        int p = pmap[b * NCLS + v];
        if (p >= 0) {
            const float* fb = feats + ((size_t)(b * CHN) << 14) + n;
            float dot = 0, nv = 0;
            if (D == 16) {
                float x[16];
#pragma unroll
                for (int d = 0; d < 16; ++d) x[d] = fb[(size_t)chan[d] << 14];
#pragma unroll
                for (int d = 0; d < 16; ++d) {
                    float y = ppd[p * 16 + d];
                    dot += x[d] * y; nv += x[d] * x[d];
                }
            } else {
                for (int d = 0; d < D; ++d) {
                    float x = fb[(size_t)chan[d] << 14];
                    float y = ppd[p * 16 + d];
                    dot += x * y; nv += x * x;
                }
            }
            float den = fmaxf(sqrtf(nv) * nr[p], 1e-8f);
            term = (1.0 - (double)(dot / den)) / ((double)Lp[p] * (double)P);
        }
    }
    red[tid] = term; __syncthreads();
    for (int s = 128; s > 0; s >>= 1) { if (tid < s) red[tid] += red[tid + s]; __syncthreads(); }
    if (tid == 0) accpart[blockIdx.x] = red[0];
}

__global__ __launch_bounds__(256) void k_finish(const double* __restrict__ accpart,
                                                float* __restrict__ out) {
    __shared__ double red[256];
    int tid = threadIdx.x;
    double s = 0;
    for (int i = tid; i < 513; i += 256) s += accpart[i];
    red[tid] = s; __syncthreads();
    for (int st = 128; st > 0; st >>= 1) { if (tid < st) red[tid] += red[tid + st]; __syncthreads(); }
    if (tid == 0) out[0] = (float)red[0];
}

extern "C" void kernel_launch(void* const* d_in, const int* in_sizes, int n_in,
                              void* d_out, int out_size, void* d_ws, size_t ws_size,
                              hipStream_t stream) {
    const float* feats  = (const float*)d_in[0];
    const int* predict  = (const int*)d_in[2];
    char* ws = (char*)d_ws;
    double* accpart = (double*)ws;
    int* plan       = (int*)(ws + 8192);
    ull* thrKey     = (ull*)(ws + 12288);
    float* pos_sum  = (float*)(ws + 16384);
    int* counts2    = (int*)(ws + 24576);
    float* cert     = (float*)(ws + 65536);
    float* out      = (float*)d_out;

    k_cert       <<<512, 256, 0, stream>>>(feats, predict, cert, counts2);
    k_sel        <<<129, 512, 0, stream>>>(predict, cert, counts2, plan, thrKey, pos_sum);
    k_accum      <<<256, 512, 0, stream>>>(feats, predict, cert, plan, thrKey, pos_sum);
    k_interintra <<<513, 256, 0, stream>>>(feats, predict, plan, pos_sum, accpart);
    k_finish     <<<1,   256, 0, stream>>>(accpart, out);
}